// Round 9
// baseline (298.723 us; speedup 1.0000x reference)
//
#include <hip/hip_runtime.h>
#include <hip/hip_bf16.h>

typedef __attribute__((ext_vector_type(8))) short short8;
typedef __attribute__((ext_vector_type(4))) short short4v;
typedef __attribute__((ext_vector_type(4))) float float4v;
typedef __attribute__((ext_vector_type(2))) unsigned int uint2v;

#define LDS_BYTES 138240
// LDS arena (bytes):
//  Xbf : [64][264] bf16 @ 0      (33792) — live whole kernel (residual)
//  Vt  : 8 x [32][72] bf16 @ 33792 (36864) — per-head V^T, k-PERMUTED storage
//  Q   : [64][264] bf16 @ 70656  (33792)
//  K   : [64][264] bf16 @ 104448 (33792)
//  CTX : [64][264] bf16 @ 33792  (33792) — aliases Vt after PV done
//  Y   : [64][260] f32  @ 70656  (66560) — aliases Q+K after PV barrier
// P1/P5 work split: wave (h,half) -> rows [32*half,+32) x cols [32h,+32)
// (halves per-wave A-frag LDS reads vs col-only split; weight loads double but hit L2)
#define XBF_OFF   0
#define VT_OFF    33792
#define Q_OFF     70656
#define K_OFF     104448
#define CTX_OFF   33792
#define Y_OFF     70656

__device__ __forceinline__ unsigned short f2bf_rn(float f) {
    union { __hip_bfloat16 b; unsigned short u; } v;
    v.b = __float2bfloat16(f);
    return v.u;
}
__device__ __forceinline__ unsigned int pk2bf(float a, float b) {
    union { __hip_bfloat162 h; unsigned int u; } v;
    v.h = __float22bfloat162_rn(make_float2(a, b));
    return v.u;
}
__device__ __forceinline__ float bf2f(unsigned short h) {
    union { unsigned int u; float f; } v; v.u = ((unsigned int)h) << 16;
    return v.f;
}
union U8 { unsigned int u[4]; short8 s; };

// Pre-convert weights fp32 -> bf16 in MFMA B-fragment order:
// elem index = ((ks*16 + nt2)*64 + lane)*8 + j ; c = ks*32 + (lane>>4)*8 + j ;
// o = nt2*16 + (lane&15) ; value = W[c*256 + o].
__global__ void prep_weights(const float* __restrict__ wq, const float* __restrict__ wk,
                             const float* __restrict__ wv, const float* __restrict__ wo,
                             unsigned short* __restrict__ wfrag) {
    int tid = blockIdx.x * 256 + threadIdx.x;
    if (tid >= 4 * 65536) return;
    int m = tid >> 16;
    int e = tid & 65535;
    int j = e & 7;
    int lane = (e >> 3) & 63;
    int nt2 = (e >> 9) & 15;
    int ks = e >> 13;
    int c = ks * 32 + (lane >> 4) * 8 + j;
    int o = nt2 * 16 + (lane & 15);
    const float* W = (m == 0) ? wq : (m == 1) ? wk : (m == 2) ? wv : wo;
    wfrag[tid] = f2bf_rn(W[c * 256 + o]);
}

__global__ __launch_bounds__(1024, 4) void swin_fused(
    const float* __restrict__ x,
    const unsigned short* __restrict__ wfrag,
    const float* __restrict__ bq, const float* __restrict__ bk,
    const float* __restrict__ bv, const float* __restrict__ bo,
    const float* __restrict__ gamma, const float* __restrict__ beta,
    float* __restrict__ out)
{
    extern __shared__ char smem[];
    const int tid = threadIdx.x;
    const int w    = tid >> 6;    // wave id 0..15
    const int h    = w & 7;       // head / 32-col group
    const int half = w >> 3;      // token(row)-half
    const int l   = tid & 63;
    const int l15 = l & 15;
    const int l4  = l >> 4;

    const int blk = blockIdx.x;
    const int bb  = blk >> 8;
    const int wh  = (blk >> 4) & 15;
    const int ww  = blk & 15;

    unsigned short* Xbf = (unsigned short*)(smem + XBF_OFF);

    // ---- Phase 0: stage X (fp32 -> bf16), shifted-window gather, rows 49..63 zero ----
    for (int idx = tid; idx < 64 * 64; idx += 1024) {
        const int tok = idx >> 6;
        const int c4  = idx & 63;
        float4v f = (float4v){0.f, 0.f, 0.f, 0.f};
        if (tok < 49) {
            const int i = tok / 7;
            const int j = tok - 7 * i;
            int gr = wh * 7 + i + 3; if (gr >= 112) gr -= 112;
            int gc = ww * 7 + j + 3; if (gc >= 112) gc -= 112;
            f = *(const float4v*)(x + (((size_t)bb * 112 + gr) * 112 + gc) * 256 + c4 * 4);
        }
        uint2v u;
        u.x = pk2bf(f.x, f.y);
        u.y = pk2bf(f.z, f.w);
        *(uint2v*)(Xbf + tok * 264 + c4 * 4) = u;
    }
    __syncthreads();   // B0

    unsigned short* Qs = (unsigned short*)(smem + Q_OFF);
    unsigned short* Ks = (unsigned short*)(smem + K_OFF);
    unsigned short* Vt = (unsigned short*)(smem + VT_OFF);

    // ---- Phase 1: QKV projection, row-col split: rows [32half,+32) x cols [32h,+32) ----
    {
        float4v accQ[2][2], accK[2][2], accV[2][2];
#pragma unroll
        for (int mt = 0; mt < 2; ++mt)
#pragma unroll
            for (int nt = 0; nt < 2; ++nt) {
                accQ[mt][nt] = (float4v){0.f, 0.f, 0.f, 0.f};
                accK[mt][nt] = (float4v){0.f, 0.f, 0.f, 0.f};
                accV[mt][nt] = (float4v){0.f, 0.f, 0.f, 0.f};
            }
        const unsigned short* wqf = wfrag;
        const unsigned short* wkf = wfrag + 65536;
        const unsigned short* wvf = wfrag + 2 * 65536;
#pragma unroll
        for (int ks = 0; ks < 8; ++ks) {
            short8 bq_[2], bk_[2], bv_[2];
#pragma unroll
            for (int nt = 0; nt < 2; ++nt) {
                const int woff = ((ks * 16 + 2 * h + nt) * 64 + l) * 8;
                bq_[nt] = *(const short8*)(wqf + woff);
                bk_[nt] = *(const short8*)(wkf + woff);
                bv_[nt] = *(const short8*)(wvf + woff);
            }
            short8 afr[2];
#pragma unroll
            for (int mt = 0; mt < 2; ++mt)
                afr[mt] = *(const short8*)(Xbf + (32 * half + mt * 16 + l15) * 264 + ks * 32 + l4 * 8);
            __builtin_amdgcn_s_setprio(1);
#pragma unroll
            for (int mt = 0; mt < 2; ++mt)
#pragma unroll
                for (int nt = 0; nt < 2; ++nt) {
                    accQ[mt][nt] = __builtin_amdgcn_mfma_f32_16x16x32_bf16(afr[mt], bq_[nt], accQ[mt][nt], 0, 0, 0);
                    accK[mt][nt] = __builtin_amdgcn_mfma_f32_16x16x32_bf16(afr[mt], bk_[nt], accK[mt][nt], 0, 0, 0);
                    accV[mt][nt] = __builtin_amdgcn_mfma_f32_16x16x32_bf16(afr[mt], bv_[nt], accV[mt][nt], 0, 0, 0);
                }
            __builtin_amdgcn_s_setprio(0);
        }
#pragma unroll
        for (int nt = 0; nt < 2; ++nt) {
            const int o = 32 * h + nt * 16 + l15;
            const float biasq = bq[o];
            const float biask = bk[o];
            const float biasv = bv[o];
#pragma unroll
            for (int mt = 0; mt < 2; ++mt) {
                const int tok0 = 32 * half + mt * 16 + l4 * 4;
#pragma unroll
                for (int r = 0; r < 4; ++r) {
                    Qs[(tok0 + r) * 264 + o] = f2bf_rn(accQ[mt][nt][r] + biasq);
                    Ks[(tok0 + r) * 264 + o] = f2bf_rn(accK[mt][nt][r] + biask);
                }
                // V: per-head transposed + permuted: tok=32half+16mt+4l4+r -> kk=32half+8l4+4mt+r
                uint2v u;
                u.x = pk2bf(accV[mt][nt][0] + biasv, accV[mt][nt][1] + biasv);
                u.y = pk2bf(accV[mt][nt][2] + biasv, accV[mt][nt][3] + biasv);
                *(uint2v*)(Vt + h * 2304 + (nt * 16 + l15) * 72 + 32 * half + 8 * l4 + 4 * mt) = u;
            }
        }
    }
    __syncthreads();   // B1: Q/K (cross-half rows) and Vt visible

    // ---- Phase 2: S^T = K Q^T. sa[mt][nt]: row k_tok = mt*16+l4*4+r, col q = 32*half+nt*16+l15 ----
    float4v sa[4][2];
#pragma unroll
    for (int mt = 0; mt < 4; ++mt)
#pragma unroll
        for (int nt = 0; nt < 2; ++nt)
            sa[mt][nt] = (float4v){0.f, 0.f, 0.f, 0.f};
    {
        short8 kfr[4], qfr[2];
#pragma unroll
        for (int mt = 0; mt < 4; ++mt)
            kfr[mt] = *(const short8*)(Ks + (mt * 16 + l15) * 264 + 32 * h + l4 * 8);
#pragma unroll
        for (int nt = 0; nt < 2; ++nt)
            qfr[nt] = *(const short8*)(Qs + (32 * half + nt * 16 + l15) * 264 + 32 * h + l4 * 8);
        __builtin_amdgcn_s_setprio(1);
#pragma unroll
        for (int mt = 0; mt < 4; ++mt)
#pragma unroll
            for (int nt = 0; nt < 2; ++nt)
                sa[mt][nt] = __builtin_amdgcn_mfma_f32_16x16x32_bf16(kfr[mt], qfr[nt], sa[mt][nt], 0, 0, 0);
        __builtin_amdgcn_s_setprio(0);
    }
    // NO barrier: Q/K are not overwritten until after B3.

    // ---- Phase 3: in-register softmax over k + build PV A-frags in registers ----
    // pa[nt][ks] elem j (bf16): P[q=32half+nt*16+l15][k = 32ks + 16*(j>>2) + 4*l4 + (j&3)]
    short8 pa[2][2];
    const float SCALE = 0.17677669529663687f;  // 1/sqrt(32)
#pragma unroll
    for (int nt = 0; nt < 2; ++nt) {
        float sv[4][4];
        float mx = -1e30f;
#pragma unroll
        for (int mt = 0; mt < 4; ++mt)
#pragma unroll
            for (int r = 0; r < 4; ++r) {
                // k = mt*16 + l4*4 + r ; valid iff k < 49
                const bool valid = (mt < 3) || ((l4 == 0) && (r == 0));
                sv[mt][r] = valid ? sa[mt][nt][r] * SCALE : -1e30f;
                mx = fmaxf(mx, sv[mt][r]);
            }
        mx = fmaxf(mx, __shfl_xor(mx, 16, 64));
        mx = fmaxf(mx, __shfl_xor(mx, 32, 64));
        float p[4][4];
        float sum = 0.f;
#pragma unroll
        for (int mt = 0; mt < 4; ++mt)
#pragma unroll
            for (int r = 0; r < 4; ++r) {
                p[mt][r] = __expf(sv[mt][r] - mx);   // exp(-1e30 - mx) == 0, masks k>=49
                sum += p[mt][r];
            }
        sum += __shfl_xor(sum, 16, 64);
        sum += __shfl_xor(sum, 32, 64);
        const float inv = 1.f / sum;
        U8 t0, t1;
        t0.u[0] = pk2bf(p[0][0] * inv, p[0][1] * inv);
        t0.u[1] = pk2bf(p[0][2] * inv, p[0][3] * inv);
        t0.u[2] = pk2bf(p[1][0] * inv, p[1][1] * inv);
        t0.u[3] = pk2bf(p[1][2] * inv, p[1][3] * inv);
        t1.u[0] = pk2bf(p[2][0] * inv, p[2][1] * inv);
        t1.u[1] = pk2bf(p[2][2] * inv, p[2][3] * inv);
        t1.u[2] = pk2bf(p[3][0] * inv, p[3][1] * inv);
        t1.u[3] = pk2bf(p[3][2] * inv, p[3][3] * inv);
        pa[nt][0] = t0.s;   // k-block 0..31  (mt 0,1)
        pa[nt][1] = t1.s;   // k-block 32..63 (mt 2,3)
    }

    // ---- Phase 4: ctx rows [32*half,+32) = P V; Vt permuted storage -> single b128 B-frag ----
    float4v ca[2][2];
#pragma unroll
    for (int mtl = 0; mtl < 2; ++mtl)
#pragma unroll
        for (int nt = 0; nt < 2; ++nt)
            ca[mtl][nt] = (float4v){0.f, 0.f, 0.f, 0.f};
#pragma unroll
    for (int ks = 0; ks < 2; ++ks) {
#pragma unroll
        for (int ntv = 0; ntv < 2; ++ntv) {
            short8 bfr = *(const short8*)(Vt + h * 2304 + (ntv * 16 + l15) * 72 + ks * 32 + l4 * 8);
            __builtin_amdgcn_s_setprio(1);
#pragma unroll
            for (int mtl = 0; mtl < 2; ++mtl)
                ca[mtl][ntv] = __builtin_amdgcn_mfma_f32_16x16x32_bf16(pa[mtl][ks], bfr, ca[mtl][ntv], 0, 0, 0);
            __builtin_amdgcn_s_setprio(0);
        }
    }
    __syncthreads();   // B3: all Q/K reads (P2) and Vt reads (P4) done -> Ctx/Y may overwrite

    // ---- write ctx bf16 packed [64][264] ----
    unsigned short* Ctx = (unsigned short*)(smem + CTX_OFF);
#pragma unroll
    for (int nt = 0; nt < 2; ++nt) {
        const int o = 32 * h + nt * 16 + l15;
#pragma unroll
        for (int mtl = 0; mtl < 2; ++mtl) {
            const int tok0 = (2 * half + mtl) * 16 + l4 * 4;
            Ctx[(tok0 + 0) * 264 + o] = f2bf_rn(ca[mtl][nt][0]);
            Ctx[(tok0 + 1) * 264 + o] = f2bf_rn(ca[mtl][nt][1]);
            Ctx[(tok0 + 2) * 264 + o] = f2bf_rn(ca[mtl][nt][2]);
            Ctx[(tok0 + 3) * 264 + o] = f2bf_rn(ca[mtl][nt][3]);
        }
    }
    __syncthreads();   // B4: Ctx visible

    // ---- Phase 5: out-proj, row-col split: rows [32half,+32) x cout [32h,+32) ----
    float4v oa[2][2];
#pragma unroll
    for (int g = 0; g < 2; ++g)
#pragma unroll
        for (int ct = 0; ct < 2; ++ct)
            oa[g][ct] = (float4v){0.f, 0.f, 0.f, 0.f};
    const unsigned short* womat = wfrag + 3 * 65536;
#pragma unroll
    for (int ks = 0; ks < 8; ++ks) {
        short8 bfr[2];
#pragma unroll
        for (int ct = 0; ct < 2; ++ct)
            bfr[ct] = *(const short8*)(womat + ((ks * 16 + 2 * h + ct) * 64 + l) * 8);
        short8 afr[2];
#pragma unroll
        for (int g = 0; g < 2; ++g)
            afr[g] = *(const short8*)(Ctx + (32 * half + g * 16 + l15) * 264 + ks * 32 + l4 * 8);
        __builtin_amdgcn_s_setprio(1);
#pragma unroll
        for (int g = 0; g < 2; ++g)
#pragma unroll
            for (int ct = 0; ct < 2; ++ct)
                oa[g][ct] = __builtin_amdgcn_mfma_f32_16x16x32_bf16(afr[g], bfr[ct], oa[g][ct], 0, 0, 0);
        __builtin_amdgcn_s_setprio(0);
    }
    // y = attn + bo -> Y fp32 [64][260] (residual added in LN phase from Xbf)
    float* Y = (float*)(smem + Y_OFF);
#pragma unroll
    for (int ct = 0; ct < 2; ++ct) {
        const int cout = 32 * h + ct * 16 + l15;
        const float bias = bo[cout];
#pragma unroll
        for (int g = 0; g < 2; ++g)
#pragma unroll
            for (int r = 0; r < 4; ++r) {
                const int tok = 32 * half + g * 16 + l4 * 4 + r;
                Y[tok * 260 + cout] = oa[g][ct][r] + bias;
            }
    }
    __syncthreads();   // B5: Y cross-wave for LN

    // ---- Phase 6: LayerNorm per token (one token per wave), residual from Xbf, coalesced ----
    const float4v g4  = *(const float4v*)(gamma + l * 4);
    const float4v be4 = *(const float4v*)(beta + l * 4);
#pragma unroll
    for (int t = 0; t < 4; ++t) {
        const int tok = w + t * 16;
        if (tok < 49) {
            float4v f = *(const float4v*)(Y + tok * 260 + l * 4);
            short4v xr = *(const short4v*)(Xbf + tok * 264 + l * 4);
            f.x += bf2f((unsigned short)xr.x);
            f.y += bf2f((unsigned short)xr.y);
            f.z += bf2f((unsigned short)xr.z);
            f.w += bf2f((unsigned short)xr.w);
            float sum = f.x + f.y + f.z + f.w;
            float sq  = f.x * f.x + f.y * f.y + f.z * f.z + f.w * f.w;
#pragma unroll
            for (int msk = 1; msk < 64; msk <<= 1) {
                sum += __shfl_xor(sum, msk, 64);
                sq  += __shfl_xor(sq,  msk, 64);
            }
            const float mu   = sum * (1.f / 256.f);
            const float var  = sq * (1.f / 256.f) - mu * mu;
            const float rstd = rsqrtf(var + 1e-3f);
            const int i = tok / 7;
            const int j = tok - 7 * i;
            int gr = wh * 7 + i + 3; if (gr >= 112) gr -= 112;
            int gc = ww * 7 + j + 3; if (gc >= 112) gc -= 112;
            float4v o4;
            o4.x = (f.x - mu) * rstd * g4.x + be4.x;
            o4.y = (f.y - mu) * rstd * g4.y + be4.y;
            o4.z = (f.z - mu) * rstd * g4.z + be4.z;
            o4.w = (f.w - mu) * rstd * g4.w + be4.w;
            *(float4v*)(out + (((size_t)bb * 112 + gr) * 112 + gc) * 256 + l * 4) = o4;
        }
    }
}

extern "C" void kernel_launch(void* const* d_in, const int* in_sizes, int n_in,
                              void* d_out, int out_size, void* d_ws, size_t ws_size,
                              hipStream_t stream) {
    const float* x     = (const float*)d_in[0];
    const float* wq    = (const float*)d_in[1];
    const float* bq    = (const float*)d_in[2];
    const float* wk    = (const float*)d_in[3];
    const float* bk    = (const float*)d_in[4];
    const float* wv    = (const float*)d_in[5];
    const float* bv    = (const float*)d_in[6];
    const float* wo    = (const float*)d_in[7];
    const float* bo    = (const float*)d_in[8];
    const float* gamma = (const float*)d_in[9];
    const float* beta  = (const float*)d_in[10];
    float* out = (float*)d_out;
    unsigned short* wfrag = (unsigned short*)d_ws;   // 4 * 65536 bf16 = 512 KB

    prep_weights<<<1024, 256, 0, stream>>>(wq, wk, wv, wo, wfrag);

    hipFuncSetAttribute((const void*)swin_fused,
                        hipFuncAttributeMaxDynamicSharedMemorySize, LDS_BYTES);
    swin_fused<<<4096, 1024, LDS_BYTES, stream>>>(x, wfrag, bq, bk, bv, bo, gamma, beta, out);
}

// Round 10
// 269.003 us; speedup vs baseline: 1.1105x; 1.1105x over previous
//
#include <hip/hip_runtime.h>
#include <hip/hip_bf16.h>

typedef __attribute__((ext_vector_type(8))) short short8;
typedef __attribute__((ext_vector_type(4))) short short4v;
typedef __attribute__((ext_vector_type(4))) float float4v;
typedef __attribute__((ext_vector_type(2))) unsigned int uint2v;

#define LDS_BYTES 138240
// LDS arena (bytes):
//  Xbf : [64][264] bf16 @ 0      (33792) — live whole kernel (residual)
//  Vt  : 8 x [32][72] bf16 @ 33792 (36864) — per-head V^T, k-PERMUTED storage
//  Q   : [64][264] bf16 @ 70656  (33792)
//  K   : [64][264] bf16 @ 104448 (33792)
//  CTX : [64][264] bf16 @ 33792  (33792) — aliases Vt after PV done
//  Y   : [64][260] f32  @ 70656  (66560) — aliases Q+K after PV barrier
// P1 trick: Q/K computed as Q^T = mfma(W_frag, X_frag) (operand swap; A/B lane maps
// are identical) -> C holds 4 consecutive OUTPUT CHANNELS per lane -> b64 stores.
#define XBF_OFF   0
#define VT_OFF    33792
#define Q_OFF     70656
#define K_OFF     104448
#define CTX_OFF   33792
#define Y_OFF     70656

__device__ __forceinline__ unsigned short f2bf_rn(float f) {
    union { __hip_bfloat16 b; unsigned short u; } v;
    v.b = __float2bfloat16(f);
    return v.u;
}
__device__ __forceinline__ unsigned int pk2bf(float a, float b) {
    union { __hip_bfloat162 h; unsigned int u; } v;
    v.h = __float22bfloat162_rn(make_float2(a, b));
    return v.u;
}
__device__ __forceinline__ float bf2f(unsigned short h) {
    union { unsigned int u; float f; } v; v.u = ((unsigned int)h) << 16;
    return v.f;
}
union U8 { unsigned int u[4]; short8 s; };

// Pre-convert weights fp32 -> bf16 in MFMA B-fragment order:
// elem index = ((ks*16 + nt2)*64 + lane)*8 + j ; c = ks*32 + (lane>>4)*8 + j ;
// o = nt2*16 + (lane&15) ; value = W[c*256 + o].
__global__ void prep_weights(const float* __restrict__ wq, const float* __restrict__ wk,
                             const float* __restrict__ wv, const float* __restrict__ wo,
                             unsigned short* __restrict__ wfrag) {
    int tid = blockIdx.x * 256 + threadIdx.x;
    if (tid >= 4 * 65536) return;
    int m = tid >> 16;
    int e = tid & 65535;
    int j = e & 7;
    int lane = (e >> 3) & 63;
    int nt2 = (e >> 9) & 15;
    int ks = e >> 13;
    int c = ks * 32 + (lane >> 4) * 8 + j;
    int o = nt2 * 16 + (lane & 15);
    const float* W = (m == 0) ? wq : (m == 1) ? wk : (m == 2) ? wv : wo;
    wfrag[tid] = f2bf_rn(W[c * 256 + o]);
}

__global__ __launch_bounds__(1024, 4) void swin_fused(
    const float* __restrict__ x,
    const unsigned short* __restrict__ wfrag,
    const float* __restrict__ bq, const float* __restrict__ bk,
    const float* __restrict__ bv, const float* __restrict__ bo,
    const float* __restrict__ gamma, const float* __restrict__ beta,
    float* __restrict__ out)
{
    extern __shared__ char smem[];
    const int tid = threadIdx.x;
    const int w    = tid >> 6;    // wave id 0..15
    const int h    = w & 7;       // head
    const int half = w >> 3;      // token-half
    const int l   = tid & 63;
    const int l15 = l & 15;
    const int l4  = l >> 4;
    const int nt2 = 2 * h + half; // 16-col output group owned by this wave

    const int blk = blockIdx.x;
    const int bb  = blk >> 8;
    const int wh  = (blk >> 4) & 15;
    const int ww  = blk & 15;

    unsigned short* Xbf = (unsigned short*)(smem + XBF_OFF);

    // ---- Phase 0: stage X (fp32 -> bf16), shifted-window gather, rows 49..63 zero ----
    for (int idx = tid; idx < 64 * 64; idx += 1024) {
        const int tok = idx >> 6;
        const int c4  = idx & 63;
        float4v f = (float4v){0.f, 0.f, 0.f, 0.f};
        if (tok < 49) {
            const int i = tok / 7;
            const int j = tok - 7 * i;
            int gr = wh * 7 + i + 3; if (gr >= 112) gr -= 112;
            int gc = ww * 7 + j + 3; if (gc >= 112) gc -= 112;
            f = *(const float4v*)(x + (((size_t)bb * 112 + gr) * 112 + gc) * 256 + c4 * 4);
        }
        uint2v u;
        u.x = pk2bf(f.x, f.y);
        u.y = pk2bf(f.z, f.w);
        *(uint2v*)(Xbf + tok * 264 + c4 * 4) = u;
    }
    __syncthreads();   // B0

    unsigned short* Qs = (unsigned short*)(smem + Q_OFF);
    unsigned short* Ks = (unsigned short*)(smem + K_OFF);
    unsigned short* Vt = (unsigned short*)(smem + VT_OFF);

    // ---- Phase 1: QKV projection, ks-outer (each X A-frag read once, feeds Q,K,V).
    //      Q/K use swapped-operand MFMA (output = Q^T slab) -> b64 channel-contiguous stores.
    {
        float4v accQ[4], accK[4], accV[4];
#pragma unroll
        for (int mt = 0; mt < 4; ++mt) {
            accQ[mt] = (float4v){0.f, 0.f, 0.f, 0.f};
            accK[mt] = (float4v){0.f, 0.f, 0.f, 0.f};
            accV[mt] = (float4v){0.f, 0.f, 0.f, 0.f};
        }
        const unsigned short* wqf = wfrag;
        const unsigned short* wkf = wfrag + 65536;
        const unsigned short* wvf = wfrag + 2 * 65536;
#pragma unroll
        for (int ks = 0; ks < 8; ++ks) {
            const int woff = ((ks * 16 + nt2) * 64 + l) * 8;
            short8 bq_ = *(const short8*)(wqf + woff);
            short8 bk_ = *(const short8*)(wkf + woff);
            short8 bv_ = *(const short8*)(wvf + woff);
            short8 afr[4];
#pragma unroll
            for (int mt = 0; mt < 4; ++mt)
                afr[mt] = *(const short8*)(Xbf + (mt * 16 + l15) * 264 + ks * 32 + l4 * 8);
            __builtin_amdgcn_s_setprio(1);
#pragma unroll
            for (int mt = 0; mt < 4; ++mt)
                accQ[mt] = __builtin_amdgcn_mfma_f32_16x16x32_bf16(bq_, afr[mt], accQ[mt], 0, 0, 0);
#pragma unroll
            for (int mt = 0; mt < 4; ++mt)
                accK[mt] = __builtin_amdgcn_mfma_f32_16x16x32_bf16(bk_, afr[mt], accK[mt], 0, 0, 0);
#pragma unroll
            for (int mt = 0; mt < 4; ++mt)
                accV[mt] = __builtin_amdgcn_mfma_f32_16x16x32_bf16(afr[mt], bv_, accV[mt], 0, 0, 0);
            __builtin_amdgcn_s_setprio(0);
        }
        // Q/K: output layout (o = nt2*16 + 4*l4 + r, tok = mt*16 + l15) -> b64 stores
        const int o0 = nt2 * 16 + 4 * l4;
        const float4v bq4 = *(const float4v*)(bq + o0);
        const float4v bk4 = *(const float4v*)(bk + o0);
#pragma unroll
        for (int mt = 0; mt < 4; ++mt) {
            const int tok = mt * 16 + l15;
            uint2v uq;
            uq.x = pk2bf(accQ[mt][0] + bq4.x, accQ[mt][1] + bq4.y);
            uq.y = pk2bf(accQ[mt][2] + bq4.z, accQ[mt][3] + bq4.w);
            *(uint2v*)(Qs + tok * 264 + o0) = uq;
            uint2v uk;
            uk.x = pk2bf(accK[mt][0] + bk4.x, accK[mt][1] + bk4.y);
            uk.y = pk2bf(accK[mt][2] + bk4.z, accK[mt][3] + bk4.w);
            *(uint2v*)(Ks + tok * 264 + o0) = uk;
        }
        // V (old orientation): per-head transposed + permuted:
        // tok (mt,l4,r) -> kk = 32*(mt>>1) + 8*l4 + 4*(mt&1) + r
        const int o = nt2 * 16 + l15;
        const float biasv = bv[o];
        const int d = half * 16 + l15;
#pragma unroll
        for (int mt = 0; mt < 4; ++mt) {
            uint2v u;
            u.x = pk2bf(accV[mt][0] + biasv, accV[mt][1] + biasv);
            u.y = pk2bf(accV[mt][2] + biasv, accV[mt][3] + biasv);
            *(uint2v*)(Vt + h * 2304 + d * 72 + 32 * (mt >> 1) + 8 * l4 + 4 * (mt & 1)) = u;
        }
    }
    __syncthreads();   // B1: Q/K (cross-half) and Vt (pair) visible

    // ---- Phase 2: S^T = K Q^T. sa[mt][nt]: row k_tok = mt*16+l4*4+r, col q = 32*half+nt*16+l15 ----
    float4v sa[4][2];
#pragma unroll
    for (int mt = 0; mt < 4; ++mt)
#pragma unroll
        for (int nt = 0; nt < 2; ++nt)
            sa[mt][nt] = (float4v){0.f, 0.f, 0.f, 0.f};
    {
        short8 kfr[4], qfr[2];
#pragma unroll
        for (int mt = 0; mt < 4; ++mt)
            kfr[mt] = *(const short8*)(Ks + (mt * 16 + l15) * 264 + 32 * h + l4 * 8);
#pragma unroll
        for (int nt = 0; nt < 2; ++nt)
            qfr[nt] = *(const short8*)(Qs + (32 * half + nt * 16 + l15) * 264 + 32 * h + l4 * 8);
        __builtin_amdgcn_s_setprio(1);
#pragma unroll
        for (int mt = 0; mt < 4; ++mt)
#pragma unroll
            for (int nt = 0; nt < 2; ++nt)
                sa[mt][nt] = __builtin_amdgcn_mfma_f32_16x16x32_bf16(kfr[mt], qfr[nt], sa[mt][nt], 0, 0, 0);
        __builtin_amdgcn_s_setprio(0);
    }
    // NO barrier: Q/K are not overwritten until after B3.

    // ---- Phase 3: in-register softmax over k + build PV A-frags in registers ----
    // pa[nt][ks] elem j (bf16): P[q=32half+nt*16+l15][k = 32ks + 16*(j>>2) + 4*l4 + (j&3)]
    short8 pa[2][2];
    const float SCALE = 0.17677669529663687f;  // 1/sqrt(32)
#pragma unroll
    for (int nt = 0; nt < 2; ++nt) {
        float sv[4][4];
        float mx = -1e30f;
#pragma unroll
        for (int mt = 0; mt < 4; ++mt)
#pragma unroll
            for (int r = 0; r < 4; ++r) {
                // k = mt*16 + l4*4 + r ; valid iff k < 49
                const bool valid = (mt < 3) || ((l4 == 0) && (r == 0));
                sv[mt][r] = valid ? sa[mt][nt][r] * SCALE : -1e30f;
                mx = fmaxf(mx, sv[mt][r]);
            }
        mx = fmaxf(mx, __shfl_xor(mx, 16, 64));
        mx = fmaxf(mx, __shfl_xor(mx, 32, 64));
        float p[4][4];
        float sum = 0.f;
#pragma unroll
        for (int mt = 0; mt < 4; ++mt)
#pragma unroll
            for (int r = 0; r < 4; ++r) {
                p[mt][r] = __expf(sv[mt][r] - mx);   // exp(-1e30 - mx) == 0, masks k>=49
                sum += p[mt][r];
            }
        sum += __shfl_xor(sum, 16, 64);
        sum += __shfl_xor(sum, 32, 64);
        const float inv = 1.f / sum;
        U8 t0, t1;
        t0.u[0] = pk2bf(p[0][0] * inv, p[0][1] * inv);
        t0.u[1] = pk2bf(p[0][2] * inv, p[0][3] * inv);
        t0.u[2] = pk2bf(p[1][0] * inv, p[1][1] * inv);
        t0.u[3] = pk2bf(p[1][2] * inv, p[1][3] * inv);
        t1.u[0] = pk2bf(p[2][0] * inv, p[2][1] * inv);
        t1.u[1] = pk2bf(p[2][2] * inv, p[2][3] * inv);
        t1.u[2] = pk2bf(p[3][0] * inv, p[3][1] * inv);
        t1.u[3] = pk2bf(p[3][2] * inv, p[3][3] * inv);
        pa[nt][0] = t0.s;   // k-block 0..31  (mt 0,1)
        pa[nt][1] = t1.s;   // k-block 32..63 (mt 2,3)
    }

    // ---- Phase 4: ctx rows [32*half,+32) = P V; Vt permuted storage -> single b128 B-frag ----
    float4v ca[2][2];
#pragma unroll
    for (int mtl = 0; mtl < 2; ++mtl)
#pragma unroll
        for (int nt = 0; nt < 2; ++nt)
            ca[mtl][nt] = (float4v){0.f, 0.f, 0.f, 0.f};
#pragma unroll
    for (int ks = 0; ks < 2; ++ks) {
#pragma unroll
        for (int ntv = 0; ntv < 2; ++ntv) {
            short8 bfr = *(const short8*)(Vt + h * 2304 + (ntv * 16 + l15) * 72 + ks * 32 + l4 * 8);
            __builtin_amdgcn_s_setprio(1);
#pragma unroll
            for (int mtl = 0; mtl < 2; ++mtl)
                ca[mtl][ntv] = __builtin_amdgcn_mfma_f32_16x16x32_bf16(pa[mtl][ks], bfr, ca[mtl][ntv], 0, 0, 0);
            __builtin_amdgcn_s_setprio(0);
        }
    }
    __syncthreads();   // B3: all Q/K reads (P2) and Vt reads (P4) done -> Ctx/Y may overwrite

    // ---- Prefetch P5 weight frags (global, no deps on Ctx) to hide L2 latency under B4 ----
    const unsigned short* womat = wfrag + 3 * 65536;
    short8 wpre[8];
#pragma unroll
    for (int ks = 0; ks < 8; ++ks)
        wpre[ks] = *(const short8*)(womat + ((ks * 16 + nt2) * 64 + l) * 8);

    // ---- write ctx bf16 packed [64][264] ----
    unsigned short* Ctx = (unsigned short*)(smem + CTX_OFF);
#pragma unroll
    for (int nt = 0; nt < 2; ++nt) {
        const int o = 32 * h + nt * 16 + l15;
#pragma unroll
        for (int mtl = 0; mtl < 2; ++mtl) {
            const int tok0 = (2 * half + mtl) * 16 + l4 * 4;
            Ctx[(tok0 + 0) * 264 + o] = f2bf_rn(ca[mtl][nt][0]);
            Ctx[(tok0 + 1) * 264 + o] = f2bf_rn(ca[mtl][nt][1]);
            Ctx[(tok0 + 2) * 264 + o] = f2bf_rn(ca[mtl][nt][2]);
            Ctx[(tok0 + 3) * 264 + o] = f2bf_rn(ca[mtl][nt][3]);
        }
    }
    __syncthreads();   // B4: Ctx visible

    // ---- Phase 5: out-proj: wave -> cout [16*nt2, +16), all 64 rows ----
    float4v oa[4];
#pragma unroll
    for (int mt = 0; mt < 4; ++mt) oa[mt] = (float4v){0.f, 0.f, 0.f, 0.f};
#pragma unroll
    for (int ks = 0; ks < 8; ++ks) {
        short8 afr[4];
#pragma unroll
        for (int mt = 0; mt < 4; ++mt)
            afr[mt] = *(const short8*)(Ctx + (mt * 16 + l15) * 264 + ks * 32 + l4 * 8);
        __builtin_amdgcn_s_setprio(1);
#pragma unroll
        for (int mt = 0; mt < 4; ++mt)
            oa[mt] = __builtin_amdgcn_mfma_f32_16x16x32_bf16(afr[mt], wpre[ks], oa[mt], 0, 0, 0);
        __builtin_amdgcn_s_setprio(0);
    }
    // y = attn + bo -> Y fp32 [64][260] (residual added in LN phase from Xbf)
    float* Y = (float*)(smem + Y_OFF);
    {
        const int cout = nt2 * 16 + l15;
        const float bias = bo[cout];
#pragma unroll
        for (int mt = 0; mt < 4; ++mt)
#pragma unroll
            for (int r = 0; r < 4; ++r) {
                const int tok = mt * 16 + l4 * 4 + r;
                Y[tok * 260 + cout] = oa[mt][r] + bias;
            }
    }
    __syncthreads();   // B5: Y cross-wave for LN

    // ---- Phase 6: LayerNorm per token (one token per wave), residual from Xbf, coalesced ----
    const float4v g4  = *(const float4v*)(gamma + l * 4);
    const float4v be4 = *(const float4v*)(beta + l * 4);
#pragma unroll
    for (int t = 0; t < 4; ++t) {
        const int tok = w + t * 16;
        if (tok < 49) {
            float4v f = *(const float4v*)(Y + tok * 260 + l * 4);
            short4v xr = *(const short4v*)(Xbf + tok * 264 + l * 4);
            f.x += bf2f((unsigned short)xr.x);
            f.y += bf2f((unsigned short)xr.y);
            f.z += bf2f((unsigned short)xr.z);
            f.w += bf2f((unsigned short)xr.w);
            float sum = f.x + f.y + f.z + f.w;
            float sq  = f.x * f.x + f.y * f.y + f.z * f.z + f.w * f.w;
#pragma unroll
            for (int msk = 1; msk < 64; msk <<= 1) {
                sum += __shfl_xor(sum, msk, 64);
                sq  += __shfl_xor(sq,  msk, 64);
            }
            const float mu   = sum * (1.f / 256.f);
            const float var  = sq * (1.f / 256.f) - mu * mu;
            const float rstd = rsqrtf(var + 1e-3f);
            const int i = tok / 7;
            const int j = tok - 7 * i;
            int gr = wh * 7 + i + 3; if (gr >= 112) gr -= 112;
            int gc = ww * 7 + j + 3; if (gc >= 112) gc -= 112;
            float4v o4;
            o4.x = (f.x - mu) * rstd * g4.x + be4.x;
            o4.y = (f.y - mu) * rstd * g4.y + be4.y;
            o4.z = (f.z - mu) * rstd * g4.z + be4.z;
            o4.w = (f.w - mu) * rstd * g4.w + be4.w;
            *(float4v*)(out + (((size_t)bb * 112 + gr) * 112 + gc) * 256 + l * 4) = o4;
        }
    }
}

extern "C" void kernel_launch(void* const* d_in, const int* in_sizes, int n_in,
                              void* d_out, int out_size, void* d_ws, size_t ws_size,
                              hipStream_t stream) {
    const float* x     = (const float*)d_in[0];
    const float* wq    = (const float*)d_in[1];
    const float* bq    = (const float*)d_in[2];
    const float* wk    = (const float*)d_in[3];
    const float* bk    = (const float*)d_in[4];
    const float* wv    = (const float*)d_in[5];
    const float* bv    = (const float*)d_in[6];
    const float* wo    = (const float*)d_in[7];
    const float* bo    = (const float*)d_in[8];
    const float* gamma = (const float*)d_in[9];
    const float* beta  = (const float*)d_in[10];
    float* out = (float*)d_out;
    unsigned short* wfrag = (unsigned short*)d_ws;   // 4 * 65536 bf16 = 512 KB

    prep_weights<<<1024, 256, 0, stream>>>(wq, wk, wv, wo, wfrag);

    hipFuncSetAttribute((const void*)swin_fused,
                        hipFuncAttributeMaxDynamicSharedMemorySize, LDS_BYTES);
    swin_fused<<<4096, 1024, LDS_BYTES, stream>>>(x, wfrag, bq, bk, bv, bo, gamma, beta, out);
}